// Round 2
// baseline (1539.539 us; speedup 1.0000x reference)
//
#include <hip/hip_runtime.h>

#define NN 20000
#define NE 40000
#define NGR 1000
#define FDIM 32

typedef unsigned short u16;
typedef u16 u16x8 __attribute__((ext_vector_type(8)));
typedef __bf16 bf16x8 __attribute__((ext_vector_type(8)));
typedef float f32x4 __attribute__((ext_vector_type(4)));

union U8 { u16x8 u; bf16x8 b; };

__device__ __forceinline__ u16 f2bf(float f) {
    union { float f; unsigned u; } v; v.f = f;
    unsigned r = v.u + 0x7FFF + ((v.u >> 16) & 1);   // RNE
    return (u16)(r >> 16);
}
__device__ __forceinline__ float bf2f(u16 h) {
    union { unsigned u; float f; } v; v.u = ((unsigned)h) << 16;
    return v.f;
}
__device__ __forceinline__ float sigmoidf(float x) { return 1.f / (1.f + __expf(-x)); }

// ---------------- lin0: h = relu(x @ W0^T + b0); also bf16 copy ----------------
__global__ __launch_bounds__(256) void k_lin0(const float* __restrict__ x,
    const float* __restrict__ W0, const float* __restrict__ b0,
    float* __restrict__ h, u16* __restrict__ outb)
{
    int wid = (blockIdx.x * blockDim.x + threadIdx.x) >> 6;
    int lane = threadIdx.x & 63;
    if (wid >= NN) return;
    float xv = (lane < FDIM) ? x[wid * FDIM + lane] : 0.f;
    const float* w = W0 + lane * FDIM;
    float acc = b0[lane];
#pragma unroll
    for (int f = 0; f < FDIM; ++f)
        acc += __shfl(xv, f, 64) * w[f];
    float r = fmaxf(acc, 0.f);
    h[wid * 64 + lane] = r;
    outb[wid * 64 + lane] = f2bf(r);
}

// ---------------- edge MLP: h1 = relu(ea @ We1^T + be1), bf16 [E,128] ----------
__global__ __launch_bounds__(256) void k_edge_mlp(const float* __restrict__ ea,
    const float* __restrict__ We1, const float* __restrict__ be1,
    u16* __restrict__ h1)
{
    int idx = blockIdx.x * 256 + threadIdx.x;
    if (idx >= NE * 128) return;
    int e = idx >> 7, k = idx & 127;
    float acc = be1[k];
#pragma unroll
    for (int j = 0; j < 5; ++j)
        acc += ea[e * 5 + j] * We1[k * 5 + j];
    h1[idx] = f2bf(fmaxf(acc, 0.f));
}

// ---------------- Wt[o][kk] = bf16(We2[(kk>>7)*64 + o, kk&127]), [64,8192] -----
__global__ __launch_bounds__(256) void k_wt(const float* __restrict__ We2,
    u16* __restrict__ Wt)
{
    int idx = blockIdx.x * 256 + threadIdx.x;   // 64*8192
    int o = idx >> 13, kk = idx & 8191;
    int i = kk >> 7, k = kk & 127;
    Wt[idx] = f2bf(We2[(i * 64 + o) * 128 + k]);
}

// ---------------- degree ----------------
__global__ __launch_bounds__(256) void k_deg(const int* __restrict__ ei, float* __restrict__ deg)
{
    int idx = blockIdx.x * 256 + threadIdx.x;
    if (idx < NE) atomicAdd(&deg[ei[NE + idx]], 1.f);
}
__global__ __launch_bounds__(256) void k_invdeg(float* __restrict__ deg)
{
    int idx = blockIdx.x * 256 + threadIdx.x;
    if (idx < NN) deg[idx] = 1.f / fmaxf(deg[idx], 1.f);
}

// ---------------- graph node ranges (batch is sorted) ----------------
__global__ __launch_bounds__(256) void k_ranges(const int* __restrict__ batch,
    int* __restrict__ gstart, int* __restrict__ gend)
{
    int idx = blockIdx.x * 256 + threadIdx.x;
    if (idx >= NN) return;
    int b = batch[idx];
    if (idx == 0 || batch[idx - 1] != b) gstart[b] = idx;
    if (idx == NN - 1 || batch[idx + 1] != b) gend[b] = idx + 1;
}

// ---------------- node bias: nb[n,o] = sum_i h[n,i]*be2[i*64+o] ----------------
__global__ __launch_bounds__(256) void k_nbias(const float* __restrict__ h,
    const float* __restrict__ be2, float* __restrict__ nb)
{
    int wid = (blockIdx.x * blockDim.x + threadIdx.x) >> 6;
    int lane = threadIdx.x & 63;
    if (wid >= NN) return;
    float hv = h[wid * 64 + lane];
    float acc = 0.f;
#pragma unroll 16
    for (int i = 0; i < 64; ++i)
        acc += __shfl(hv, i, 64) * be2[i * 64 + lane];
    nb[wid * 64 + lane] = acc;
}

// ---------------- fused message GEMM + aggregate --------------------------------
// msg[e,o] = sum_kk z[e,kk]*Wt[o][kk] + nb[src,o], z[e,kk]=outb[src,kk>>7]*h1[e,kk&127]
// 128 edges/block, K=8192 in 64 chunks of 128; mfma 16x16x32 bf16, XOR swizzle.
__global__ __launch_bounds__(256, 2) void k_msg(
    const u16* __restrict__ outb, const u16* __restrict__ h1,
    const u16* __restrict__ Wt, const int* __restrict__ ei,
    const float* __restrict__ nb, float* __restrict__ agg)
{
    __shared__ __align__(16) u16 sh[128 * 72];    // hsrc bf16, pad 72 (2-way max)
    __shared__ __align__(16) u16 sh1[128 * 128];  // h1 tile, xor-swizzled
    __shared__ __align__(16) u16 sw[64 * 128];    // Wt chunk, xor-swizzled
    __shared__ int sdst[128];
    __shared__ int ssrc[128];
    const int t = threadIdx.x;
    const int eb0 = blockIdx.x * 128;

    if (t < 128) {
        int e = eb0 + t; int s = 0, d = 0;
        if (e < NE) { s = ei[e]; d = ei[NE + e]; }
        ssrc[t] = s; sdst[t] = d;
    }
#pragma unroll
    for (int r = 0; r < 4; ++r) {                 // gather out[src] : 128 x 8 chunks
        int cid = t + 256 * r;
        int row = cid >> 3, c8 = cid & 7;
        int e = eb0 + row;
        u16x8 v = {};
        if (e < NE) { int s = ei[e]; v = *(const u16x8*)(outb + (size_t)s * 64 + c8 * 8); }
        *(u16x8*)&sh[row * 72 + c8 * 8] = v;
    }
#pragma unroll
    for (int r = 0; r < 8; ++r) {                 // h1 tile: 128 x 16 chunks
        int cid = t + 256 * r;
        int row = cid >> 4, c16 = cid & 15;
        int e = eb0 + row;
        u16x8 v = {};
        if (e < NE) v = *(const u16x8*)(h1 + (size_t)e * 128 + c16 * 8);
        int pc = c16 ^ (row & 15);
        *(u16x8*)&sh1[row * 128 + pc * 8] = v;
    }
    __syncthreads();

    const int lane = t & 63, w = t >> 6, r16 = lane & 15, q = lane >> 4;
    const int m0 = w * 32;                        // wave's 2 m-subtiles
    f32x4 acc[2][4] = {};

    for (int ch = 0; ch < 64; ++ch) {
#pragma unroll
        for (int r = 0; r < 4; ++r) {             // stage Wt chunk [64][128]
            int cid = t + 256 * r;
            int row = cid >> 4, c16 = cid & 15;
            u16x8 v = *(const u16x8*)(Wt + (size_t)row * 8192 + ch * 128 + c16 * 8);
            int pc = c16 ^ (row & 15);
            *(u16x8*)&sw[row * 128 + pc * 8] = v;
        }
        __syncthreads();
#pragma unroll
        for (int s4 = 0; s4 < 4; ++s4) {
            int tg = ch * 4 + s4;                 // K-step 0..255
            int i = tg >> 2;                      // hsrc column (uniform in step)
            int c16a = (tg & 3) * 4 + q;          // h1 16B-chunk col
            bf16x8 af[2];
#pragma unroll
            for (int sub = 0; sub < 2; ++sub) {
                int m = m0 + sub * 16 + r16;      // (m&15) == r16
                float sv = bf2f(sh[m * 72 + i]);
                U8 hv; hv.u = *(const u16x8*)&sh1[m * 128 + (c16a ^ r16) * 8];
                bf16x8 a;
#pragma unroll
                for (int j = 0; j < 8; ++j) a[j] = (__bf16)(sv * bf2f(hv.u[j]));
                af[sub] = a;
            }
#pragma unroll
            for (int nt = 0; nt < 4; ++nt) {
                int o = nt * 16 + r16;            // (o&15) == r16
                U8 bv; bv.u = *(const u16x8*)&sw[o * 128 + ((s4 * 4 + q) ^ r16) * 8];
                acc[0][nt] = __builtin_amdgcn_mfma_f32_16x16x32_bf16(af[0], bv.b, acc[0][nt], 0, 0, 0);
                acc[1][nt] = __builtin_amdgcn_mfma_f32_16x16x32_bf16(af[1], bv.b, acc[1][nt], 0, 0, 0);
            }
        }
        __syncthreads();
    }
    // epilogue: D row=(q*4+reg) within subtile, col=r16 within n-tile
#pragma unroll
    for (int sub = 0; sub < 2; ++sub) {
#pragma unroll
        for (int r = 0; r < 4; ++r) {
            int m = m0 + sub * 16 + q * 4 + r;
            int e = eb0 + m;
            if (e >= NE) continue;
            int d = sdst[m], s = ssrc[m];
#pragma unroll
            for (int nt = 0; nt < 4; ++nt) {
                int o = nt * 16 + r16;
                float val = acc[sub][nt][r] + nb[(size_t)s * 64 + o];
                atomicAdd(&agg[(size_t)d * 64 + o], val);
            }
        }
    }
}

// ---------------- GRU cell (fused deg-normalize + bias + relu) ----------------
__global__ __launch_bounds__(256) void k_gru(float* __restrict__ h, u16* __restrict__ outb,
    const float* __restrict__ agg, const float* __restrict__ invdeg,
    const float* __restrict__ b_conv,
    const float* __restrict__ W_ih, const float* __restrict__ W_hh,
    const float* __restrict__ b_ih, const float* __restrict__ b_hh)
{
    int wid = (blockIdx.x * blockDim.x + threadIdx.x) >> 6;
    int lane = threadIdx.x & 63;
    if (wid >= NN) return;
    float m = fmaxf(agg[wid * 64 + lane] * invdeg[wid] + b_conv[lane], 0.f);
    float hv = h[wid * 64 + lane];
    float air = b_ih[lane], aiz = b_ih[64 + lane], ain = b_ih[128 + lane];
    float ahr = b_hh[lane], ahz = b_hh[64 + lane], ahn = b_hh[128 + lane];
    const float* wir = W_ih + lane * 64;
    const float* wiz = W_ih + (64 + lane) * 64;
    const float* win = W_ih + (128 + lane) * 64;
    const float* whr = W_hh + lane * 64;
    const float* whz = W_hh + (64 + lane) * 64;
    const float* whn = W_hh + (128 + lane) * 64;
#pragma unroll 16
    for (int i = 0; i < 64; ++i) {
        float mi = __shfl(m, i, 64), hi = __shfl(hv, i, 64);
        air += mi * wir[i]; aiz += mi * wiz[i]; ain += mi * win[i];
        ahr += hi * whr[i]; ahz += hi * whz[i]; ahn += hi * whn[i];
    }
    float r = sigmoidf(air + ahr), z = sigmoidf(aiz + ahz);
    float nn = tanhf(ain + r * ahn);
    float hnew = (1.f - z) * nn + z * hv;
    h[wid * 64 + lane] = hnew;
    outb[wid * 64 + lane] = f2bf(hnew);
}

// ---------------- Set2Set LSTM cell: wave per graph ----------------
__global__ __launch_bounds__(256) void k_lstm(float* __restrict__ hl, float* __restrict__ cl,
    const float* __restrict__ qstar,
    const float* __restrict__ W_ihl, const float* __restrict__ W_hhl,
    const float* __restrict__ b_ihl, const float* __restrict__ b_hhl)
{
    int wid = (blockIdx.x * blockDim.x + threadIdx.x) >> 6;
    int lane = threadIdx.x & 63;
    if (wid >= NGR) return;
    float q0 = qstar[wid * 128 + lane];
    float q1 = qstar[wid * 128 + 64 + lane];
    float hv = hl[wid * 64 + lane];
    float gi = b_ihl[lane] + b_hhl[lane];
    float gf = b_ihl[64 + lane] + b_hhl[64 + lane];
    float gg = b_ihl[128 + lane] + b_hhl[128 + lane];
    float go = b_ihl[192 + lane] + b_hhl[192 + lane];
    const float* wii = W_ihl + lane * 128;
    const float* wif = W_ihl + (64 + lane) * 128;
    const float* wig = W_ihl + (128 + lane) * 128;
    const float* wio = W_ihl + (192 + lane) * 128;
    const float* whi = W_hhl + lane * 64;
    const float* whf = W_hhl + (64 + lane) * 64;
    const float* whg = W_hhl + (128 + lane) * 64;
    const float* who = W_hhl + (192 + lane) * 64;
#pragma unroll 8
    for (int j = 0; j < 64; ++j) {
        float a = __shfl(q0, j, 64), b = __shfl(q1, j, 64), c = __shfl(hv, j, 64);
        gi += a * wii[j] + b * wii[64 + j] + c * whi[j];
        gf += a * wif[j] + b * wif[64 + j] + c * whf[j];
        gg += a * wig[j] + b * wig[64 + j] + c * whg[j];
        go += a * wio[j] + b * wio[64 + j] + c * who[j];
    }
    float cv = cl[wid * 64 + lane];
    cv = sigmoidf(gf) * cv + sigmoidf(gi) * tanhf(gg);
    float hnew = sigmoidf(go) * tanhf(cv);
    cl[wid * 64 + lane] = cv;
    hl[wid * 64 + lane] = hnew;
}

// ---------------- attention scores e[n] = <h[n], hl[batch[n]]> ----------------
__global__ __launch_bounds__(256) void k_escore(const float* __restrict__ h,
    const float* __restrict__ hl, const int* __restrict__ batch, float* __restrict__ ebuf)
{
    int wid = (blockIdx.x * blockDim.x + threadIdx.x) >> 6;
    int lane = threadIdx.x & 63;
    if (wid >= NN) return;
    int b = batch[wid];
    float p = h[wid * 64 + lane] * hl[b * 64 + lane];
#pragma unroll
    for (int off = 32; off > 0; off >>= 1) p += __shfl_xor(p, off, 64);
    if (lane == 0) ebuf[wid] = p;
}

// ---------------- segment softmax + weighted pool: wave per graph ----------------
__global__ __launch_bounds__(256) void k_pool(const float* __restrict__ h,
    const float* __restrict__ hl, const float* __restrict__ ebuf,
    const int* __restrict__ gstart, const int* __restrict__ gend,
    float* __restrict__ qstar)
{
    int wid = (blockIdx.x * blockDim.x + threadIdx.x) >> 6;
    int lane = threadIdx.x & 63;
    if (wid >= NGR) return;
    int s = gstart[wid], e = gend[wid];
    float mx = -3.4e38f;
    for (int n = s + lane; n < e; n += 64) mx = fmaxf(mx, ebuf[n]);
#pragma unroll
    for (int off = 32; off > 0; off >>= 1) mx = fmaxf(mx, __shfl_xor(mx, off, 64));
    float sum = 0.f;
    for (int n = s + lane; n < e; n += 64) sum += __expf(ebuf[n] - mx);
#pragma unroll
    for (int off = 32; off > 0; off >>= 1) sum += __shfl_xor(sum, off, 64);
    float inv = (sum > 0.f) ? 1.f / sum : 0.f;
    float r = 0.f;
    for (int n = s; n < e; ++n) {
        float a = __expf(ebuf[n] - mx) * inv;
        r += a * h[n * 64 + lane];
    }
    qstar[wid * 128 + lane] = hl[wid * 64 + lane];
    qstar[wid * 128 + 64 + lane] = r;
}

// ---------------- readout ----------------
__global__ __launch_bounds__(256) void k_readout(const float* __restrict__ qstar,
    const float* __restrict__ W1, const float* __restrict__ b1,
    const float* __restrict__ W2, const float* __restrict__ b2,
    float* __restrict__ outp)
{
    int wid = (blockIdx.x * blockDim.x + threadIdx.x) >> 6;
    int lane = threadIdx.x & 63;
    if (wid >= NGR) return;
    float q0 = qstar[wid * 128 + lane], q1 = qstar[wid * 128 + 64 + lane];
    float acc = b1[lane];
    const float* w = W1 + lane * 128;
#pragma unroll 8
    for (int j = 0; j < 64; ++j)
        acc += __shfl(q0, j, 64) * w[j] + __shfl(q1, j, 64) * w[64 + j];
    float y = fmaxf(acc, 0.f);
    float p = y * W2[lane];
#pragma unroll
    for (int off = 32; off > 0; off >>= 1) p += __shfl_xor(p, off, 64);
    if (lane == 0) outp[wid] = p + b2[0];
}

extern "C" void kernel_launch(void* const* d_in, const int* in_sizes, int n_in,
                              void* d_out, int out_size, void* d_ws, size_t ws_size,
                              hipStream_t stream)
{
    const float* x      = (const float*)d_in[0];
    const float* ea     = (const float*)d_in[1];
    const int*   ei     = (const int*)d_in[2];
    const int*   batch  = (const int*)d_in[3];
    const float* W0     = (const float*)d_in[4];
    const float* b0     = (const float*)d_in[5];
    const float* We1    = (const float*)d_in[6];
    const float* be1    = (const float*)d_in[7];
    const float* We2    = (const float*)d_in[8];
    const float* be2    = (const float*)d_in[9];
    const float* b_conv = (const float*)d_in[10];
    const float* W_ih   = (const float*)d_in[11];
    const float* W_hh   = (const float*)d_in[12];
    const float* b_ih   = (const float*)d_in[13];
    const float* b_hh   = (const float*)d_in[14];
    const float* W_ihl  = (const float*)d_in[15];
    const float* W_hhl  = (const float*)d_in[16];
    const float* b_ihl  = (const float*)d_in[17];
    const float* b_hhl  = (const float*)d_in[18];
    const float* W1     = (const float*)d_in[19];
    const float* b1     = (const float*)d_in[20];
    const float* W2     = (const float*)d_in[21];
    const float* b2     = (const float*)d_in[22];
    float* outp = (float*)d_out;

    char* ws = (char*)d_ws;
    size_t off = 0;
    auto alloc = [&](size_t bytes) -> char* {
        char* p = ws + off;
        off += (bytes + 255) & ~(size_t)255;
        return p;
    };
    u16*   h1     = (u16*)  alloc((size_t)NE * 128 * 2);   // 10.24 MB
    u16*   Wt     = (u16*)  alloc((size_t)64 * 8192 * 2);  // 1.05 MB
    u16*   outb   = (u16*)  alloc((size_t)NN * 64 * 2);    // 2.56 MB
    float* h      = (float*)alloc((size_t)NN * 64 * 4);    // 5.12 MB
    float* agg    = (float*)alloc((size_t)NN * 64 * 4);    // 5.12 MB
    float* nb     = (float*)alloc((size_t)NN * 64 * 4);    // 5.12 MB
    float* invdeg = (float*)alloc(NN * 4);
    float* ebuf   = (float*)alloc(NN * 4);
    int*   gstart = (int*)  alloc(NGR * 4);
    int*   gend   = (int*)  alloc(NGR * 4);
    float* hl     = (float*)alloc(NGR * 64 * 4);
    float* cl     = (float*)alloc(NGR * 64 * 4);
    float* qstar  = (float*)alloc(NGR * 128 * 4);
    if (off > ws_size) return;   // ~30.5 MB needed

    hipMemsetAsync(invdeg, 0, NN * 4, stream);
    hipMemsetAsync(gstart, 0, NGR * 4, stream);
    hipMemsetAsync(gend,   0, NGR * 4, stream);
    hipMemsetAsync(hl,     0, NGR * 64 * 4, stream);
    hipMemsetAsync(cl,     0, NGR * 64 * 4, stream);
    hipMemsetAsync(qstar,  0, NGR * 128 * 4, stream);

    k_lin0<<<(NN * 64) / 256, 256, 0, stream>>>(x, W0, b0, h, outb);
    k_edge_mlp<<<(NE * 128) / 256, 256, 0, stream>>>(ea, We1, be1, h1);
    k_wt<<<(64 * 8192) / 256, 256, 0, stream>>>(We2, Wt);
    k_deg<<<(NE + 255) / 256, 256, 0, stream>>>(ei, invdeg);
    k_invdeg<<<(NN + 255) / 256, 256, 0, stream>>>(invdeg);
    k_ranges<<<(NN + 255) / 256, 256, 0, stream>>>(batch, gstart, gend);

    for (int it = 0; it < 3; ++it) {
        k_nbias<<<(NN * 64) / 256, 256, 0, stream>>>(h, be2, nb);
        hipMemsetAsync(agg, 0, (size_t)NN * 64 * 4, stream);
        k_msg<<<(NE + 127) / 128, 256, 0, stream>>>(outb, h1, Wt, ei, nb, agg);
        k_gru<<<(NN * 64) / 256, 256, 0, stream>>>(h, outb, agg, invdeg, b_conv,
                                                   W_ih, W_hh, b_ih, b_hh);
    }
    for (int st = 0; st < 3; ++st) {
        k_lstm<<<(NGR * 64) / 256, 256, 0, stream>>>(hl, cl, qstar, W_ihl, W_hhl, b_ihl, b_hhl);
        k_escore<<<(NN * 64) / 256, 256, 0, stream>>>(h, hl, batch, ebuf);
        k_pool<<<(NGR * 64) / 256, 256, 0, stream>>>(h, hl, ebuf, gstart, gend, qstar);
    }
    k_readout<<<(NGR * 64) / 256, 256, 0, stream>>>(qstar, W1, b1, W2, b2, outp);
}

// Round 3
// 725.269 us; speedup vs baseline: 2.1227x; 2.1227x over previous
//
#include <hip/hip_runtime.h>

#define NN 20000
#define NE 40000
#define NGR 1000

typedef unsigned short u16;
typedef u16 u16x8 __attribute__((ext_vector_type(8)));
typedef __bf16 bf16x8 __attribute__((ext_vector_type(8)));
typedef float f32x4 __attribute__((ext_vector_type(4)));

union U8 { u16x8 u; bf16x8 b; };

#define WT_STRIDE 8256   // 8192 regular K + 64 bias-K columns

__device__ __forceinline__ u16 f2bf(float f) {
    union { float f; unsigned u; } v; v.f = f;
    unsigned r = v.u + 0x7FFF + ((v.u >> 16) & 1);   // RNE
    return (u16)(r >> 16);
}
__device__ __forceinline__ float bf2f(u16 h) {
    union { unsigned u; float f; } v; v.u = ((unsigned)h) << 16;
    return v.f;
}
__device__ __forceinline__ float sigmoidf(float x) { return 1.f / (1.f + __expf(-x)); }

// ---------------- one-time weight transposes (coalesced-read layouts) ----------
__global__ __launch_bounds__(256) void k_tr(
    const float* __restrict__ W_ih, const float* __restrict__ W_hh,
    const float* __restrict__ W_ihl, const float* __restrict__ W_hhl,
    const float* __restrict__ W1, const float* __restrict__ W0,
    const float* __restrict__ We1,
    float* __restrict__ WTih, float* __restrict__ WThh,
    float* __restrict__ WTihl, float* __restrict__ WThhl,
    float* __restrict__ WT1, float* __restrict__ WT0, float* __restrict__ We1T)
{
    int idx = blockIdx.x * 256 + threadIdx.x;
    if (idx < 12288) { int i = idx / 192, o = idx % 192; WTih[idx] = W_ih[o * 64 + i]; return; }
    idx -= 12288;
    if (idx < 12288) { int i = idx / 192, o = idx % 192; WThh[idx] = W_hh[o * 64 + i]; return; }
    idx -= 12288;
    if (idx < 32768) { int j = idx / 256, o = idx % 256; WTihl[idx] = W_ihl[o * 128 + j]; return; }
    idx -= 32768;
    if (idx < 16384) { int j = idx / 256, o = idx % 256; WThhl[idx] = W_hhl[o * 64 + j]; return; }
    idx -= 16384;
    if (idx < 8192) { int j = idx / 64, o = idx % 64; WT1[idx] = W1[o * 128 + j]; return; }
    idx -= 8192;
    if (idx < 2048) { int f = idx / 64, o = idx % 64; WT0[idx] = W0[o * 32 + f]; return; }
    idx -= 2048;
    if (idx < 640) { int j = idx / 128, k = idx % 128; We1T[idx] = We1[k * 5 + j]; }
}

// ---------------- lin0: h = relu(x @ W0^T + b0); also bf16 copy ----------------
__global__ __launch_bounds__(256) void k_lin0(const float* __restrict__ x,
    const float* __restrict__ WT0, const float* __restrict__ b0,
    float* __restrict__ h, u16* __restrict__ outb)
{
    int wid = (blockIdx.x * blockDim.x + threadIdx.x) >> 6;
    int lane = threadIdx.x & 63;
    if (wid >= NN) return;
    float xv = (lane < 32) ? x[wid * 32 + lane] : 0.f;
    float acc = b0[lane];
#pragma unroll
    for (int f = 0; f < 32; ++f)
        acc += __shfl(xv, f, 64) * WT0[f * 64 + lane];
    float r = fmaxf(acc, 0.f);
    h[wid * 64 + lane] = r;
    outb[wid * 64 + lane] = f2bf(r);
}

// ---------------- edge MLP: h1 = relu(ea @ We1^T + be1), bf16 [E,128] ----------
__global__ __launch_bounds__(256) void k_edge_mlp(const float* __restrict__ ea,
    const float* __restrict__ We1T, const float* __restrict__ be1,
    u16* __restrict__ h1)
{
    int idx = blockIdx.x * 256 + threadIdx.x;
    if (idx >= NE * 128) return;
    int e = idx >> 7, k = idx & 127;
    float acc = be1[k];
#pragma unroll
    for (int j = 0; j < 5; ++j)
        acc += ea[e * 5 + j] * We1T[j * 128 + k];
    h1[idx] = f2bf(fmaxf(acc, 0.f));
}

// --------- Wt_ext[o][c]: c<8192 -> bf16(We2[((c>>7)*64+o)*128 + (c&127)]);
// ---------            c in [8192,8256): bias cols = bf16(be2[(c-8192)*64+o]) ---
__global__ __launch_bounds__(256) void k_wt(const float* __restrict__ We2,
    const float* __restrict__ be2, u16* __restrict__ Wt)
{
    int c = blockIdx.x * 256 + threadIdx.x;   // 0..8447 (grid 33 blocks)
    int o = blockIdx.y;
    if (c >= WT_STRIDE) return;
    float v;
    if (c < 8192) { int i = c >> 7, k = c & 127; v = We2[(i * 64 + o) * 128 + k]; }
    else          { int i = c - 8192; v = be2[i * 64 + o]; }
    Wt[(size_t)o * WT_STRIDE + c] = f2bf(v);
}

// ---------------- degree ----------------
__global__ __launch_bounds__(256) void k_deg(const int* __restrict__ ei, float* __restrict__ deg)
{
    int idx = blockIdx.x * 256 + threadIdx.x;
    if (idx < NE) atomicAdd(&deg[ei[NE + idx]], 1.f);
}
__global__ __launch_bounds__(256) void k_invdeg(float* __restrict__ deg)
{
    int idx = blockIdx.x * 256 + threadIdx.x;
    if (idx < NN) deg[idx] = 1.f / fmaxf(deg[idx], 1.f);
}

// ---------------- graph node ranges (batch is sorted) ----------------
__global__ __launch_bounds__(256) void k_ranges(const int* __restrict__ batch,
    int* __restrict__ gstart, int* __restrict__ gend)
{
    int idx = blockIdx.x * 256 + threadIdx.x;
    if (idx >= NN) return;
    int b = batch[idx];
    if (idx == 0 || batch[idx - 1] != b) gstart[b] = idx;
    if (idx == NN - 1 || batch[idx + 1] != b) gend[b] = idx + 1;
}

// ---------------- fused message GEMM + aggregate --------------------------------
// msg[e,o] = sum_ch sv[e,ch] * (h1[e,:] . Wt[o, ch-block]) + bias-cols(out[src]).
// Block: 128 threads = 2 waves x 64 edges (4 m-subtiles); K split 4-ways by
// blockIdx.y (16 chunks of 128 each); partition 3 also applies the bias block.
// A-fragments (h1) are STATIC registers; per-chunk scalar sv applied post-MFMA.
__global__ __launch_bounds__(128, 2) void k_msg(
    const u16* __restrict__ outb, const u16* __restrict__ h1,
    const u16* __restrict__ Wt, const int* __restrict__ ei,
    float* __restrict__ agg)
{
    __shared__ __align__(16) u16 sh[128 * 72];   // out[src] rows bf16, pad 72
    __shared__ __align__(16) u16 sw[64 * 128];   // Wt chunk, xor-swizzled
    __shared__ int sdst[128];
    const int t = threadIdx.x;
    const int eb0 = blockIdx.x * 128;
    const int kh = blockIdx.y;                   // 0..3

    if (t < 128) {
        int e = eb0 + t; int d = 0;
        if (e < NE) d = ei[NE + e];
        sdst[t] = d;
    }
#pragma unroll
    for (int r = 0; r < 8; ++r) {                // gather out[src]: 128 rows x 8 chunks
        int cid = t + 128 * r;
        int row = cid >> 3, c8 = cid & 7;
        int e = eb0 + row;
        u16x8 v = {};
        if (e < NE) { int s = ei[e]; v = *(const u16x8*)(outb + (size_t)s * 64 + c8 * 8); }
        *(u16x8*)&sh[row * 72 + c8 * 8] = v;
    }

    const int lane = t & 63, w = t >> 6, r16 = lane & 15, q = lane >> 4;
    const int w64 = w * 64;

    // static A-fragments: h1 rows, k = s4*32 + q*8 + j
    u16x8 h1r[4][4];
#pragma unroll
    for (int sub = 0; sub < 4; ++sub) {
        int e = eb0 + w64 + sub * 16 + r16;
        if (e >= NE) e = NE - 1;                 // safe row; contribution zeroed by sv=0
        const u16* hp = h1 + (size_t)e * 128 + q * 8;
#pragma unroll
        for (int s4 = 0; s4 < 4; ++s4)
            h1r[sub][s4] = *(const u16x8*)(hp + s4 * 32);
    }
    f32x4 acc[4][4];
    const f32x4 z4 = {0.f, 0.f, 0.f, 0.f};
#pragma unroll
    for (int sub = 0; sub < 4; ++sub)
#pragma unroll
        for (int nt = 0; nt < 4; ++nt) acc[sub][nt] = z4;
    __syncthreads();

    for (int cc = 0; cc < 16; ++cc) {
        const int ch = kh * 16 + cc;
        // stage Wt chunk [64][128]
#pragma unroll
        for (int r = 0; r < 8; ++r) {
            int cid = t + 128 * r;
            int row = cid >> 4, c16 = cid & 15;
            u16x8 v = *(const u16x8*)(Wt + (size_t)row * WT_STRIDE + ch * 128 + c16 * 8);
            int pc = c16 ^ (row & 15);
            *(u16x8*)&sw[row * 128 + pc * 8] = v;
        }
        __syncthreads();

        f32x4 P[4][4];
#pragma unroll
        for (int sub = 0; sub < 4; ++sub)
#pragma unroll
            for (int nt = 0; nt < 4; ++nt) P[sub][nt] = z4;

#pragma unroll
        for (int s4 = 0; s4 < 4; ++s4) {
            U8 bv[4];
#pragma unroll
            for (int nt = 0; nt < 4; ++nt) {
                int o = nt * 16 + r16;
                bv[nt].u = *(const u16x8*)&sw[o * 128 + ((s4 * 4 + q) ^ r16) * 8];
            }
#pragma unroll
            for (int sub = 0; sub < 4; ++sub) {
                U8 a; a.u = h1r[sub][s4];
#pragma unroll
                for (int nt = 0; nt < 4; ++nt)
                    P[sub][nt] = __builtin_amdgcn_mfma_f32_16x16x32_bf16(
                        a.b, bv[nt].b, P[sub][nt], 0, 0, 0);
            }
        }
        // scale by sv (per output row m = w64 + sub*16 + q*4 + r) and accumulate
#pragma unroll
        for (int sub = 0; sub < 4; ++sub) {
            int mb = w64 + sub * 16 + q * 4;
            float s0 = bf2f(sh[(mb + 0) * 72 + ch]);
            float s1 = bf2f(sh[(mb + 1) * 72 + ch]);
            float s2 = bf2f(sh[(mb + 2) * 72 + ch]);
            float s3 = bf2f(sh[(mb + 3) * 72 + ch]);
#pragma unroll
            for (int nt = 0; nt < 4; ++nt) {
                acc[sub][nt][0] += s0 * P[sub][nt][0];
                acc[sub][nt][1] += s1 * P[sub][nt][1];
                acc[sub][nt][2] += s2 * P[sub][nt][2];
                acc[sub][nt][3] += s3 * P[sub][nt][3];
            }
        }
        __syncthreads();
    }

    if (kh == 3) {   // bias block: A = out[src] directly (cols 8192..8255)
        U8 bvb[2][4];
#pragma unroll
        for (int sb = 0; sb < 2; ++sb)
#pragma unroll
            for (int nt = 0; nt < 4; ++nt) {
                int o = nt * 16 + r16;
                bvb[sb][nt].u = *(const u16x8*)(Wt + (size_t)o * WT_STRIDE + 8192 + (sb * 4 + q) * 8);
            }
#pragma unroll
        for (int sub = 0; sub < 4; ++sub) {
            int m = w64 + sub * 16 + r16;
#pragma unroll
            for (int sb = 0; sb < 2; ++sb) {
                U8 a; a.u = *(const u16x8*)&sh[m * 72 + sb * 32 + q * 8];
#pragma unroll
                for (int nt = 0; nt < 4; ++nt)
                    acc[sub][nt] = __builtin_amdgcn_mfma_f32_16x16x32_bf16(
                        a.b, bvb[sb][nt].b, acc[sub][nt], 0, 0, 0);
            }
        }
    }

    // epilogue: D row = q*4+r, col = nt*16+r16
#pragma unroll
    for (int sub = 0; sub < 4; ++sub) {
#pragma unroll
        for (int r = 0; r < 4; ++r) {
            int m = w64 + sub * 16 + q * 4 + r;
            int e = eb0 + m;
            if (e >= NE) continue;
            int d = sdst[m];
#pragma unroll
            for (int nt = 0; nt < 4; ++nt)
                atomicAdd(&agg[(size_t)d * 64 + nt * 16 + r16], acc[sub][nt][r]);
        }
    }
}

// ---------------- GRU cell: 8 nodes per wave, transposed weights ----------------
__global__ __launch_bounds__(256) void k_gru(float* __restrict__ h, u16* __restrict__ outb,
    const float* __restrict__ agg, const float* __restrict__ invdeg,
    const float* __restrict__ b_conv,
    const float* __restrict__ WTih, const float* __restrict__ WThh,
    const float* __restrict__ b_ih, const float* __restrict__ b_hh)
{
    int wid = (blockIdx.x * blockDim.x + threadIdx.x) >> 6;
    int lane = threadIdx.x & 63;
    int n0 = wid * 8;
    if (n0 >= NN) return;
    float bcv = b_conv[lane];
    float m[8], hv[8];
    float air[8] = {}, aiz[8] = {}, ain[8] = {};
    float ahr[8] = {}, ahz[8] = {}, ahn[8] = {};
#pragma unroll
    for (int p = 0; p < 8; ++p) {
        int n = n0 + p;
        m[p] = fmaxf(agg[n * 64 + lane] * invdeg[n] + bcv, 0.f);
        hv[p] = h[n * 64 + lane];
    }
#pragma unroll 4
    for (int i = 0; i < 64; ++i) {
        const float* wi = WTih + i * 192;
        const float* wh = WThh + i * 192;
        float wir = wi[lane], wiz = wi[64 + lane], win = wi[128 + lane];
        float whr = wh[lane], whz = wh[64 + lane], whn = wh[128 + lane];
#pragma unroll
        for (int p = 0; p < 8; ++p) {
            float mi = __shfl(m[p], i, 64);
            float hi = __shfl(hv[p], i, 64);
            air[p] += mi * wir; aiz[p] += mi * wiz; ain[p] += mi * win;
            ahr[p] += hi * whr; ahz[p] += hi * whz; ahn[p] += hi * whn;
        }
    }
    float bir = b_ih[lane], biz = b_ih[64 + lane], bin = b_ih[128 + lane];
    float bhr = b_hh[lane], bhz = b_hh[64 + lane], bhn = b_hh[128 + lane];
#pragma unroll
    for (int p = 0; p < 8; ++p) {
        float r = sigmoidf(air[p] + bir + ahr[p] + bhr);
        float z = sigmoidf(aiz[p] + biz + ahz[p] + bhz);
        float nng = tanhf(ain[p] + bin + r * (ahn[p] + bhn));
        float hnew = (1.f - z) * nng + z * hv[p];
        h[(n0 + p) * 64 + lane] = hnew;
        outb[(n0 + p) * 64 + lane] = f2bf(hnew);
    }
}

// ---------------- Set2Set LSTM cell: wave per graph, transposed weights --------
__global__ __launch_bounds__(256) void k_lstm(float* __restrict__ hl, float* __restrict__ cl,
    const float* __restrict__ qstar,
    const float* __restrict__ WTihl, const float* __restrict__ WThhl,
    const float* __restrict__ b_ihl, const float* __restrict__ b_hhl)
{
    int wid = (blockIdx.x * blockDim.x + threadIdx.x) >> 6;
    int lane = threadIdx.x & 63;
    if (wid >= NGR) return;
    float q0 = qstar[wid * 128 + lane];
    float q1 = qstar[wid * 128 + 64 + lane];
    float hv = hl[wid * 64 + lane];
    float gi = 0.f, gf = 0.f, gg = 0.f, go = 0.f;
#pragma unroll 4
    for (int j = 0; j < 64; ++j) {
        const float* wv = WTihl + j * 256;
        float a = __shfl(q0, j, 64);
        gi += a * wv[lane]; gf += a * wv[64 + lane];
        gg += a * wv[128 + lane]; go += a * wv[192 + lane];
    }
#pragma unroll 4
    for (int j = 0; j < 64; ++j) {
        const float* wv = WTihl + (64 + j) * 256;
        float b = __shfl(q1, j, 64);
        gi += b * wv[lane]; gf += b * wv[64 + lane];
        gg += b * wv[128 + lane]; go += b * wv[192 + lane];
    }
#pragma unroll 4
    for (int j = 0; j < 64; ++j) {
        const float* wv = WThhl + j * 256;
        float c = __shfl(hv, j, 64);
        gi += c * wv[lane]; gf += c * wv[64 + lane];
        gg += c * wv[128 + lane]; go += c * wv[192 + lane];
    }
    gi += b_ihl[lane] + b_hhl[lane];
    gf += b_ihl[64 + lane] + b_hhl[64 + lane];
    gg += b_ihl[128 + lane] + b_hhl[128 + lane];
    go += b_ihl[192 + lane] + b_hhl[192 + lane];
    float cv = cl[wid * 64 + lane];
    cv = sigmoidf(gf) * cv + sigmoidf(gi) * tanhf(gg);
    float hnew = sigmoidf(go) * tanhf(cv);
    cl[wid * 64 + lane] = cv;
    hl[wid * 64 + lane] = hnew;
}

// ---------------- attention scores e[n] = <h[n], hl[batch[n]]> ----------------
__global__ __launch_bounds__(256) void k_escore(const float* __restrict__ h,
    const float* __restrict__ hl, const int* __restrict__ batch, float* __restrict__ ebuf)
{
    int wid = (blockIdx.x * blockDim.x + threadIdx.x) >> 6;
    int lane = threadIdx.x & 63;
    if (wid >= NN) return;
    int b = batch[wid];
    float p = h[wid * 64 + lane] * hl[b * 64 + lane];
#pragma unroll
    for (int off = 32; off > 0; off >>= 1) p += __shfl_xor(p, off, 64);
    if (lane == 0) ebuf[wid] = p;
}

// ---------------- segment softmax + weighted pool: wave per graph --------------
__global__ __launch_bounds__(256) void k_pool(const float* __restrict__ h,
    const float* __restrict__ hl, const float* __restrict__ ebuf,
    const int* __restrict__ gstart, const int* __restrict__ gend,
    float* __restrict__ qstar)
{
    int wid = (blockIdx.x * blockDim.x + threadIdx.x) >> 6;
    int lane = threadIdx.x & 63;
    if (wid >= NGR) return;
    int s = gstart[wid], e = gend[wid];
    float mx = -3.4e38f;
    for (int n = s + lane; n < e; n += 64) mx = fmaxf(mx, ebuf[n]);
#pragma unroll
    for (int off = 32; off > 0; off >>= 1) mx = fmaxf(mx, __shfl_xor(mx, off, 64));
    float sum = 0.f;
    for (int n = s + lane; n < e; n += 64) sum += __expf(ebuf[n] - mx);
#pragma unroll
    for (int off = 32; off > 0; off >>= 1) sum += __shfl_xor(sum, off, 64);
    float inv = (sum > 0.f) ? 1.f / sum : 0.f;
    float r = 0.f;
    for (int n = s; n < e; ++n) {
        float a = __expf(ebuf[n] - mx) * inv;
        r += a * h[n * 64 + lane];
    }
    qstar[wid * 128 + lane] = hl[wid * 64 + lane];
    qstar[wid * 128 + 64 + lane] = r;
}

// ---------------- readout ----------------
__global__ __launch_bounds__(256) void k_readout(const float* __restrict__ qstar,
    const float* __restrict__ WT1, const float* __restrict__ b1,
    const float* __restrict__ W2, const float* __restrict__ b2,
    float* __restrict__ outp)
{
    int wid = (blockIdx.x * blockDim.x + threadIdx.x) >> 6;
    int lane = threadIdx.x & 63;
    if (wid >= NGR) return;
    float q0 = qstar[wid * 128 + lane], q1 = qstar[wid * 128 + 64 + lane];
    float acc = b1[lane];
#pragma unroll 4
    for (int j = 0; j < 64; ++j)
        acc += __shfl(q0, j, 64) * WT1[j * 64 + lane]
             + __shfl(q1, j, 64) * WT1[(64 + j) * 64 + lane];
    float y = fmaxf(acc, 0.f);
    float p = y * W2[lane];
#pragma unroll
    for (int off = 32; off > 0; off >>= 1) p += __shfl_xor(p, off, 64);
    if (lane == 0) outp[wid] = p + b2[0];
}

extern "C" void kernel_launch(void* const* d_in, const int* in_sizes, int n_in,
                              void* d_out, int out_size, void* d_ws, size_t ws_size,
                              hipStream_t stream)
{
    const float* x      = (const float*)d_in[0];
    const float* ea     = (const float*)d_in[1];
    const int*   ei     = (const int*)d_in[2];
    const int*   batch  = (const int*)d_in[3];
    const float* W0     = (const float*)d_in[4];
    const float* b0     = (const float*)d_in[5];
    const float* We1    = (const float*)d_in[6];
    const float* be1    = (const float*)d_in[7];
    const float* We2    = (const float*)d_in[8];
    const float* be2    = (const float*)d_in[9];
    const float* b_conv = (const float*)d_in[10];
    const float* W_ih   = (const float*)d_in[11];
    const float* W_hh   = (const float*)d_in[12];
    const float* b_ih   = (const float*)d_in[13];
    const float* b_hh   = (const float*)d_in[14];
    const float* W_ihl  = (const float*)d_in[15];
    const float* W_hhl  = (const float*)d_in[16];
    const float* b_ihl  = (const float*)d_in[17];
    const float* b_hhl  = (const float*)d_in[18];
    const float* W1     = (const float*)d_in[19];
    const float* b1     = (const float*)d_in[20];
    const float* W2     = (const float*)d_in[21];
    const float* b2     = (const float*)d_in[22];
    float* outp = (float*)d_out;

    char* ws = (char*)d_ws;
    size_t off = 0;
    auto alloc = [&](size_t bytes) -> char* {
        char* p = ws + off;
        off += (bytes + 255) & ~(size_t)255;
        return p;
    };
    u16*   h1     = (u16*)  alloc((size_t)NE * 128 * 2);        // 10.24 MB
    u16*   Wt     = (u16*)  alloc((size_t)64 * WT_STRIDE * 2);  // 1.06 MB
    u16*   outb   = (u16*)  alloc((size_t)NN * 64 * 2);         // 2.56 MB
    float* h      = (float*)alloc((size_t)NN * 64 * 4);         // 5.12 MB
    float* agg    = (float*)alloc((size_t)NN * 64 * 4);         // 5.12 MB
    float* invdeg = (float*)alloc(NN * 4);
    float* ebuf   = (float*)alloc(NN * 4);
    int*   gstart = (int*)  alloc(NGR * 4);
    int*   gend   = (int*)  alloc(NGR * 4);
    float* hl     = (float*)alloc(NGR * 64 * 4);
    float* cl     = (float*)alloc(NGR * 64 * 4);
    float* qstar  = (float*)alloc(NGR * 128 * 4);
    float* WTih   = (float*)alloc(12288 * 4);
    float* WThh   = (float*)alloc(12288 * 4);
    float* WTihl  = (float*)alloc(32768 * 4);
    float* WThhl  = (float*)alloc(16384 * 4);
    float* WT1    = (float*)alloc(8192 * 4);
    float* WT0    = (float*)alloc(2048 * 4);
    float* We1T   = (float*)alloc(640 * 4);
    if (off > ws_size) return;   // ~25 MB needed

    hipMemsetAsync(invdeg, 0, NN * 4, stream);
    hipMemsetAsync(gstart, 0, NGR * 4, stream);
    hipMemsetAsync(gend,   0, NGR * 4, stream);
    hipMemsetAsync(hl,     0, NGR * 64 * 4, stream);
    hipMemsetAsync(cl,     0, NGR * 64 * 4, stream);
    hipMemsetAsync(qstar,  0, NGR * 128 * 4, stream);

    k_tr<<<331, 256, 0, stream>>>(W_ih, W_hh, W_ihl, W_hhl, W1, W0, We1,
                                  WTih, WThh, WTihl, WThhl, WT1, WT0, We1T);
    k_lin0<<<(NN * 64) / 256, 256, 0, stream>>>(x, WT0, b0, h, outb);
    k_edge_mlp<<<(NE * 128) / 256, 256, 0, stream>>>(ea, We1T, be1, h1);
    dim3 wgrid(33, 64, 1);
    k_wt<<<wgrid, 256, 0, stream>>>(We2, be2, Wt);
    k_deg<<<(NE + 255) / 256, 256, 0, stream>>>(ei, invdeg);
    k_invdeg<<<(NN + 255) / 256, 256, 0, stream>>>(invdeg);
    k_ranges<<<(NN + 255) / 256, 256, 0, stream>>>(batch, gstart, gend);

    dim3 mgrid((NE + 127) / 128, 4, 1);
    for (int it = 0; it < 3; ++it) {
        hipMemsetAsync(agg, 0, (size_t)NN * 64 * 4, stream);
        k_msg<<<mgrid, 128, 0, stream>>>(outb, h1, Wt, ei, agg);
        k_gru<<<(NN / 8 * 64) / 256, 256, 0, stream>>>(h, outb, agg, invdeg, b_conv,
                                                       WTih, WThh, b_ih, b_hh);
    }
    for (int st = 0; st < 3; ++st) {
        k_lstm<<<(NGR * 64) / 256, 256, 0, stream>>>(hl, cl, qstar, WTihl, WThhl, b_ihl, b_hhl);
        k_escore<<<(NN * 64) / 256, 256, 0, stream>>>(h, hl, batch, ebuf);
        k_pool<<<(NGR * 64) / 256, 256, 0, stream>>>(h, hl, ebuf, gstart, gend, qstar);
    }
    k_readout<<<(NGR * 64) / 256, 256, 0, stream>>>(qstar, WT1, b1, W2, b2, outp);
}

// Round 4
// 725.117 us; speedup vs baseline: 2.1232x; 1.0002x over previous
//
#include <hip/hip_runtime.h>

#define NN 20000
#define NE 40000
#define NGR 1000

typedef unsigned short u16;
typedef u16 u16x8 __attribute__((ext_vector_type(8)));
typedef __bf16 bf16x8 __attribute__((ext_vector_type(8)));
typedef float f32x4 __attribute__((ext_vector_type(4)));

union U8 { u16x8 u; bf16x8 b; };

#define WT_STRIDE 8256   // 8192 regular K + 64 bias-K columns

__device__ __forceinline__ u16 f2bf(float f) {
    union { float f; unsigned u; } v; v.f = f;
    unsigned r = v.u + 0x7FFF + ((v.u >> 16) & 1);   // RNE
    return (u16)(r >> 16);
}
__device__ __forceinline__ float bf2f(u16 h) {
    union { unsigned u; float f; } v; v.u = ((unsigned)h) << 16;
    return v.f;
}
__device__ __forceinline__ float sigmoidf(float x) { return 1.f / (1.f + __expf(-x)); }

// ============ fused one-time preamble: roles dispatched by blockIdx.x ============
// [0,320): weight transposes  [320,5320): lin0  [5320,25320): edge_mlp
// [25320,27384): Wt gen  [27384,27541): deg  [27541,27620): ranges
// [27620,28870): zero agg  [28870,29870): zero hl/cl/qstar
__global__ __launch_bounds__(256) void k_pre(
    const float* __restrict__ x, const float* __restrict__ ea,
    const int* __restrict__ ei, const int* __restrict__ batch,
    const float* __restrict__ W0, const float* __restrict__ b0,
    const float* __restrict__ We1, const float* __restrict__ be1,
    const float* __restrict__ We2, const float* __restrict__ be2,
    const float* __restrict__ W_ih, const float* __restrict__ W_hh,
    const float* __restrict__ W_ihl, const float* __restrict__ W_hhl,
    const float* __restrict__ W1,
    float* __restrict__ h, u16* __restrict__ outb, u16* __restrict__ h1,
    u16* __restrict__ Wt, float* __restrict__ deg,
    int* __restrict__ gstart, int* __restrict__ gend,
    float* __restrict__ WTih, float* __restrict__ WThh,
    float* __restrict__ WTihl, float* __restrict__ WThhl, float* __restrict__ WT1,
    float* __restrict__ agg, float* __restrict__ hl, float* __restrict__ cl,
    float* __restrict__ qstar)
{
    __shared__ float wt0[32 * 64];
    __shared__ float sb0[64];
    int b = blockIdx.x;
    const int t = threadIdx.x;

    if (b < 320) {                                   // weight transposes
        int idx = b * 256 + t;
        if (idx < 12288) { WTih[idx] = W_ih[(idx % 192) * 64 + idx / 192]; return; }
        idx -= 12288;
        if (idx < 12288) { WThh[idx] = W_hh[(idx % 192) * 64 + idx / 192]; return; }
        idx -= 12288;
        if (idx < 32768) { WTihl[idx] = W_ihl[(idx % 256) * 128 + idx / 256]; return; }
        idx -= 32768;
        if (idx < 16384) { WThhl[idx] = W_hhl[(idx % 256) * 64 + idx / 256]; return; }
        idx -= 16384;
        if (idx < 8192) { WT1[idx] = W1[(idx % 64) * 128 + idx / 64]; }
        return;
    }
    b -= 320;
    if (b < 5000) {                                  // lin0: 4 nodes/block
#pragma unroll
        for (int r = 0; r < 8; ++r) {
            int idx = t + 256 * r;                   // W0 [64][32] row-major
            wt0[(idx & 31) * 64 + (idx >> 5)] = W0[idx];
        }
        if (t < 64) sb0[t] = b0[t];
        __syncthreads();
        int wid = t >> 6, lane = t & 63;
        int n = b * 4 + wid;
        float xv = (lane < 32) ? x[n * 32 + lane] : 0.f;
        float acc = sb0[lane];
#pragma unroll
        for (int f = 0; f < 32; ++f)
            acc += __shfl(xv, f, 64) * wt0[f * 64 + lane];
        float rv = fmaxf(acc, 0.f);
        h[n * 64 + lane] = rv;
        outb[n * 64 + lane] = f2bf(rv);
        return;
    }
    b -= 5000;
    if (b < 20000) {                                 // edge MLP: idx over NE*128
        int idx = b * 256 + t;
        int e = idx >> 7, k = idx & 127;
        float acc = be1[k];
#pragma unroll
        for (int j = 0; j < 5; ++j)
            acc += ea[e * 5 + j] * We1[k * 5 + j];
        h1[idx] = f2bf(fmaxf(acc, 0.f));
        return;
    }
    b -= 20000;
    if (b < 2064) {                                  // Wt gen: idx over 64*8256
        int idx = b * 256 + t;
        int o = idx / WT_STRIDE, c = idx % WT_STRIDE;
        float v = (c < 8192) ? We2[((c >> 7) * 64 + o) * 128 + (c & 127)]
                             : be2[(c - 8192) * 64 + o];
        Wt[idx] = f2bf(v);
        return;
    }
    b -= 2064;
    if (b < 157) {                                   // degree
        int idx = b * 256 + t;
        if (idx < NE) atomicAdd(&deg[ei[NE + idx]], 1.f);
        return;
    }
    b -= 157;
    if (b < 79) {                                    // graph ranges (batch sorted)
        int idx = b * 256 + t;
        if (idx < NN) {
            int bg = batch[idx];
            if (idx == 0 || batch[idx - 1] != bg) gstart[bg] = idx;
            if (idx == NN - 1 || batch[idx + 1] != bg) gend[bg] = idx + 1;
        }
        return;
    }
    b -= 79;
    if (b < 1250) {                                  // zero agg (float4)
        f32x4 z = {0.f, 0.f, 0.f, 0.f};
        ((f32x4*)agg)[b * 256 + t] = z;
        return;
    }
    b -= 1250;
    {                                                // zero hl/cl/qstar
        int idx = b * 256 + t;
        if (idx < 64000) hl[idx] = 0.f;
        else if (idx < 128000) cl[idx - 64000] = 0.f;
        else qstar[idx - 128000] = 0.f;
    }
}

// ---------------- fused message GEMM + aggregate --------------------------------
// msg[e,o] = sum_ch sv[e,ch] * (h1[e,:] . Wt[o, ch-block]) + bias-cols(out[src]).
// 128 edges/block (2 waves x 4 subtiles); K split 4-ways by blockIdx.y.
// Wt chunk register-prefetched during MFMA, then ds_write (latency-hidden staging).
__global__ __launch_bounds__(128) void k_msg(
    const u16* __restrict__ outb, const u16* __restrict__ h1,
    const u16* __restrict__ Wt, const int* __restrict__ ei,
    float* __restrict__ agg)
{
    __shared__ __align__(16) u16 sh[128 * 72];   // sv rows (out[src]) bf16
    __shared__ __align__(16) u16 sw[64 * 128];   // Wt chunk, xor-swizzled
    __shared__ int sdst[128];
    const int t = threadIdx.x;
    const int eb0 = blockIdx.x * 128;
    const int kh = blockIdx.y;                   // 0..3

    {
        int e = eb0 + t;
        sdst[t] = (e < NE) ? ei[NE + e] : 0;
    }
#pragma unroll
    for (int r = 0; r < 8; ++r) {                // gather out[src]: 128 rows x 8 chunks
        int cid = t + 128 * r;
        int row = cid >> 3, c8 = cid & 7;
        int e = eb0 + row;
        u16x8 v = {};
        if (e < NE) { int s = ei[e]; v = *(const u16x8*)(outb + (size_t)s * 64 + c8 * 8); }
        *(u16x8*)&sh[row * 72 + c8 * 8] = v;
    }

    const int lane = t & 63, w = t >> 6, r16 = lane & 15, q = lane >> 4;
    const int w64 = w * 64;

    // static A-fragments: h1 rows, k = s4*32 + q*8 + j
    u16x8 h1r[4][4];
#pragma unroll
    for (int sub = 0; sub < 4; ++sub) {
        int e = eb0 + w64 + sub * 16 + r16;
        if (e >= NE) e = NE - 1;                 // contribution zeroed via sv=0
        const u16* hp = h1 + (size_t)e * 128 + q * 8;
#pragma unroll
        for (int s4 = 0; s4 < 4; ++s4)
            h1r[sub][s4] = *(const u16x8*)(hp + s4 * 32);
    }

    // stage first chunk
    {
        u16x8 cur[8];
#pragma unroll
        for (int r = 0; r < 8; ++r) {
            int cid = t + 128 * r;
            int row = cid >> 4, c16 = cid & 15;
            cur[r] = *(const u16x8*)(Wt + (size_t)row * WT_STRIDE + (kh * 16) * 128 + c16 * 8);
        }
#pragma unroll
        for (int r = 0; r < 8; ++r) {
            int cid = t + 128 * r;
            int row = cid >> 4, c16 = cid & 15;
            int pc = c16 ^ (row & 15);
            *(u16x8*)&sw[row * 128 + pc * 8] = cur[r];
        }
    }

    f32x4 acc[4][4];
    const f32x4 z4 = {0.f, 0.f, 0.f, 0.f};
#pragma unroll
    for (int sub = 0; sub < 4; ++sub)
#pragma unroll
        for (int nt = 0; nt < 4; ++nt) acc[sub][nt] = z4;
    __syncthreads();

    for (int cc = 0; cc < 16; ++cc) {
        const int ch = kh * 16 + cc;
        u16x8 nxt[8];
        if (cc < 15) {                           // register prefetch of next chunk
#pragma unroll
            for (int r = 0; r < 8; ++r) {
                int cid = t + 128 * r;
                int row = cid >> 4, c16 = cid & 15;
                nxt[r] = *(const u16x8*)(Wt + (size_t)row * WT_STRIDE + (ch + 1) * 128 + c16 * 8);
            }
        }

        f32x4 P[4][4];
#pragma unroll
        for (int sub = 0; sub < 4; ++sub)
#pragma unroll
            for (int nt = 0; nt < 4; ++nt) P[sub][nt] = z4;

#pragma unroll
        for (int s4 = 0; s4 < 4; ++s4) {
            U8 bv[4];
#pragma unroll
            for (int nt = 0; nt < 4; ++nt) {
                int o = nt * 16 + r16;
                bv[nt].u = *(const u16x8*)&sw[o * 128 + ((s4 * 4 + q) ^ r16) * 8];
            }
#pragma unroll
            for (int sub = 0; sub < 4; ++sub) {
                U8 a; a.u = h1r[sub][s4];
#pragma unroll
                for (int nt = 0; nt < 4; ++nt)
                    P[sub][nt] = __builtin_amdgcn_mfma_f32_16x16x32_bf16(
                        a.b, bv[nt].b, P[sub][nt], 0, 0, 0);
            }
        }
        // scale by sv (row m = w64 + sub*16 + q*4 + r) and accumulate
#pragma unroll
        for (int sub = 0; sub < 4; ++sub) {
            int mb = w64 + sub * 16 + q * 4;
            float s0 = bf2f(sh[(mb + 0) * 72 + ch]);
            float s1 = bf2f(sh[(mb + 1) * 72 + ch]);
            float s2 = bf2f(sh[(mb + 2) * 72 + ch]);
            float s3 = bf2f(sh[(mb + 3) * 72 + ch]);
#pragma unroll
            for (int nt = 0; nt < 4; ++nt) {
                acc[sub][nt][0] += s0 * P[sub][nt][0];
                acc[sub][nt][1] += s1 * P[sub][nt][1];
                acc[sub][nt][2] += s2 * P[sub][nt][2];
                acc[sub][nt][3] += s3 * P[sub][nt][3];
            }
        }
        __syncthreads();                         // readers done with sw
        if (cc < 15) {
#pragma unroll
            for (int r = 0; r < 8; ++r) {
                int cid = t + 128 * r;
                int row = cid >> 4, c16 = cid & 15;
                int pc = c16 ^ (row & 15);
                *(u16x8*)&sw[row * 128 + pc * 8] = nxt[r];
            }
            __syncthreads();                     // new chunk visible
        }
    }

    if (kh == 3) {   // bias block: A = out[src], B = Wt cols 8192..8255 (direct global)
        U8 bvb[2][4];
#pragma unroll
        for (int sb = 0; sb < 2; ++sb)
#pragma unroll
            for (int nt = 0; nt < 4; ++nt) {
                int o = nt * 16 + r16;
                bvb[sb][nt].u = *(const u16x8*)(Wt + (size_t)o * WT_STRIDE + 8192 + (sb * 4 + q) * 8);
            }
#pragma unroll
        for (int sub = 0; sub < 4; ++sub) {
            int m = w64 + sub * 16 + r16;
#pragma unroll
            for (int sb = 0; sb < 2; ++sb) {
                U8 a; a.u = *(const u16x8*)&sh[m * 72 + sb * 32 + q * 8];
#pragma unroll
                for (int nt = 0; nt < 4; ++nt)
                    acc[sub][nt] = __builtin_amdgcn_mfma_f32_16x16x32_bf16(
                        a.b, bvb[sb][nt].b, acc[sub][nt], 0, 0, 0);
            }
        }
    }

    // epilogue: D row = q*4+r, col = nt*16+r16
#pragma unroll
    for (int sub = 0; sub < 4; ++sub) {
#pragma unroll
        for (int r = 0; r < 4; ++r) {
            int m = w64 + sub * 16 + q * 4 + r;
            int e = eb0 + m;
            if (e >= NE) continue;
            int d = sdst[m];
#pragma unroll
            for (int nt = 0; nt < 4; ++nt)
                atomicAdd(&agg[(size_t)d * 64 + nt * 16 + r16], acc[sub][nt][r]);
        }
    }
}

// ---------------- GRU cell: 16 nodes/wave; folds deg-norm; re-zeroes agg --------
__global__ __launch_bounds__(256) void k_gru(float* __restrict__ h, u16* __restrict__ outb,
    float* __restrict__ agg, const float* __restrict__ deg,
    const float* __restrict__ b_conv,
    const float* __restrict__ WTih, const float* __restrict__ WThh,
    const float* __restrict__ b_ih, const float* __restrict__ b_hh)
{
    int wid = (blockIdx.x * blockDim.x + threadIdx.x) >> 6;
    int lane = threadIdx.x & 63;
    int n0 = wid * 16;
    if (n0 >= NN) return;
    float bcv = b_conv[lane];
    float m[16], hv[16];
    float air[16] = {}, aiz[16] = {}, ain[16] = {};
    float ahr[16] = {}, ahz[16] = {}, ahn[16] = {};
#pragma unroll
    for (int p = 0; p < 16; ++p) {
        int n = n0 + p;
        float invd = 1.f / fmaxf(deg[n], 1.f);
        m[p] = fmaxf(agg[n * 64 + lane] * invd + bcv, 0.f);
        agg[n * 64 + lane] = 0.f;                // re-zero for next iteration
        hv[p] = h[n * 64 + lane];
    }
#pragma unroll 2
    for (int i = 0; i < 64; ++i) {
        const float* wi = WTih + i * 192;
        const float* wh = WThh + i * 192;
        float wir = wi[lane], wiz = wi[64 + lane], win = wi[128 + lane];
        float whr = wh[lane], whz = wh[64 + lane], whn = wh[128 + lane];
#pragma unroll
        for (int p = 0; p < 16; ++p) {
            float mi = __shfl(m[p], i, 64);
            float hi = __shfl(hv[p], i, 64);
            air[p] += mi * wir; aiz[p] += mi * wiz; ain[p] += mi * win;
            ahr[p] += hi * whr; ahz[p] += hi * whz; ahn[p] += hi * whn;
        }
    }
    float bir = b_ih[lane], biz = b_ih[64 + lane], bin = b_ih[128 + lane];
    float bhr = b_hh[lane], bhz = b_hh[64 + lane], bhn = b_hh[128 + lane];
#pragma unroll
    for (int p = 0; p < 16; ++p) {
        float r = sigmoidf(air[p] + bir + ahr[p] + bhr);
        float z = sigmoidf(aiz[p] + biz + ahz[p] + bhz);
        float nng = tanhf(ain[p] + bin + r * (ahn[p] + bhn));
        float hnew = (1.f - z) * nng + z * hv[p];
        h[(n0 + p) * 64 + lane] = hnew;
        outb[(n0 + p) * 64 + lane] = f2bf(hnew);
    }
}

// ---------------- Set2Set LSTM cell: 8 graphs/wave ------------------------------
__global__ __launch_bounds__(256) void k_lstm(float* __restrict__ hl, float* __restrict__ cl,
    const float* __restrict__ qstar,
    const float* __restrict__ WTihl, const float* __restrict__ WThhl,
    const float* __restrict__ b_ihl, const float* __restrict__ b_hhl)
{
    int wid = (blockIdx.x * blockDim.x + threadIdx.x) >> 6;
    int lane = threadIdx.x & 63;
    if (wid >= NGR / 8) return;
    int g0 = wid * 8;
    float q0[8], q1[8], hv[8];
    float gi[8] = {}, gf[8] = {}, gg[8] = {}, go[8] = {};
#pragma unroll
    for (int p = 0; p < 8; ++p) {
        q0[p] = qstar[(g0 + p) * 128 + lane];
        q1[p] = qstar[(g0 + p) * 128 + 64 + lane];
        hv[p] = hl[(g0 + p) * 64 + lane];
    }
#pragma unroll 2
    for (int j = 0; j < 64; ++j) {
        const float* wv = WTihl + j * 256;
        float wi = wv[lane], wf = wv[64 + lane], wg = wv[128 + lane], wo = wv[192 + lane];
#pragma unroll
        for (int p = 0; p < 8; ++p) {
            float a = __shfl(q0[p], j, 64);
            gi[p] += a * wi; gf[p] += a * wf; gg[p] += a * wg; go[p] += a * wo;
        }
    }
#pragma unroll 2
    for (int j = 0; j < 64; ++j) {
        const float* wv = WTihl + (64 + j) * 256;
        float wi = wv[lane], wf = wv[64 + lane], wg = wv[128 + lane], wo = wv[192 + lane];
#pragma unroll
        for (int p = 0; p < 8; ++p) {
            float a = __shfl(q1[p], j, 64);
            gi[p] += a * wi; gf[p] += a * wf; gg[p] += a * wg; go[p] += a * wo;
        }
    }
#pragma unroll 2
    for (int j = 0; j < 64; ++j) {
        const float* wv = WThhl + j * 256;
        float wi = wv[lane], wf = wv[64 + lane], wg = wv[128 + lane], wo = wv[192 + lane];
#pragma unroll
        for (int p = 0; p < 8; ++p) {
            float a = __shfl(hv[p], j, 64);
            gi[p] += a * wi; gf[p] += a * wf; gg[p] += a * wg; go[p] += a * wo;
        }
    }
    float bi = b_ihl[lane] + b_hhl[lane];
    float bf = b_ihl[64 + lane] + b_hhl[64 + lane];
    float bg = b_ihl[128 + lane] + b_hhl[128 + lane];
    float bo = b_ihl[192 + lane] + b_hhl[192 + lane];
#pragma unroll
    for (int p = 0; p < 8; ++p) {
        float cv = cl[(g0 + p) * 64 + lane];
        cv = sigmoidf(gf[p] + bf) * cv + sigmoidf(gi[p] + bi) * tanhf(gg[p] + bg);
        float hnew = sigmoidf(go[p] + bo) * tanhf(cv);
        cl[(g0 + p) * 64 + lane] = cv;
        hl[(g0 + p) * 64 + lane] = hnew;
    }
}

// -------- fused attention: block(256)=4 waves per graph, online softmax ---------
__global__ __launch_bounds__(256) void k_pool(const float* __restrict__ h,
    const float* __restrict__ hl,
    const int* __restrict__ gstart, const int* __restrict__ gend,
    float* __restrict__ qstar)
{
    __shared__ float sq[64];
    __shared__ float sm[4], sl[4];
    __shared__ float sr[4][64];
    int g = blockIdx.x;
    int t = threadIdx.x, w = t >> 6, lane = t & 63;
    if (t < 64) sq[t] = hl[g * 64 + t];
    __syncthreads();
    int s = gstart[g], e = gend[g];
    float qv = sq[lane];
    float M = -3.4e38f, l = 0.f, r = 0.f;
    for (int n = s + w; n < e; n += 4) {
        float hvv = h[n * 64 + lane];
        float p = hvv * qv;
#pragma unroll
        for (int off = 32; off > 0; off >>= 1) p += __shfl_xor(p, off, 64);
        if (p > M) {
            float sc = __expf(M - p);
            l = l * sc + 1.f;
            r = r * sc + hvv;
            M = p;
        } else {
            float pe = __expf(p - M);
            l += pe;
            r += pe * hvv;
        }
    }
    if (lane == 0) { sm[w] = M; sl[w] = l; }
    sr[w][lane] = r;
    __syncthreads();
    if (w == 0) {
        float Mg = fmaxf(fmaxf(sm[0], sm[1]), fmaxf(sm[2], sm[3]));
        float lg = 0.f, rg = 0.f;
#pragma unroll
        for (int wp = 0; wp < 4; ++wp) {
            float sc = __expf(sm[wp] - Mg);      // finite sentinels: no NaN
            lg += sl[wp] * sc;
            rg += sr[wp][lane] * sc;
        }
        float inv = (lg > 0.f) ? 1.f / lg : 0.f;
        qstar[g * 128 + lane] = sq[lane];
        qstar[g * 128 + 64 + lane] = rg * inv;
    }
}

// ---------------- readout: 8 graphs/wave ----------------------------------------
__global__ __launch_bounds__(256) void k_readout(const float* __restrict__ qstar,
    const float* __restrict__ WT1, const float* __restrict__ b1,
    const float* __restrict__ W2, const float* __restrict__ b2,
    float* __restrict__ outp)
{
    int wid = (blockIdx.x * blockDim.x + threadIdx.x) >> 6;
    int lane = threadIdx.x & 63;
    if (wid >= NGR / 8) return;
    int g0 = wid * 8;
    float q0[8], q1[8], acc[8];
#pragma unroll
    for (int p = 0; p < 8; ++p) {
        q0[p] = qstar[(g0 + p) * 128 + lane];
        q1[p] = qstar[(g0 + p) * 128 + 64 + lane];
        acc[p] = b1[lane];
    }
#pragma unroll 2
    for (int j = 0; j < 64; ++j) {
        float w0v = WT1[j * 64 + lane];
        float w1v = WT1[(64 + j) * 64 + lane];
#pragma unroll
        for (int p = 0; p < 8; ++p)
            acc[p] += __shfl(q0[p], j, 64) * w0v + __shfl(q1[p], j, 64) * w1v;
    }
    float w2 = W2[lane], b2v = b2[0];
#pragma unroll
    for (int p = 0; p < 8; ++p) {
        float pr = fmaxf(acc[p], 0.f) * w2;
#pragma unroll
        for (int off = 32; off > 0; off >>= 1) pr += __shfl_xor(pr, off, 64);
        if (lane == 0) outp[g0 + p] = pr + b2v;
    }
}

extern "C" void kernel_launch(void* const* d_in, const int* in_sizes, int n_in,
                              void* d_out, int out_size, void* d_ws, size_t ws_size,
                              hipStream_t stream)
{
    const float* x      = (const float*)d_in[0];
    const float* ea     = (const float*)d_in[1];
    const int*   ei     = (const int*)d_in[2];
    const int*   batch  = (const int*)d_in[3];
    const float* W0     = (const float*)d_in[4];
    const float* b0     = (const float*)d_in[5];
    const float* We1    = (const float*)d_in[6];
    const float* be1    = (const float*)d_in[7];
    const float* We2    = (const float*)d_in[8];
    const float* be2    = (const float*)d_in[9];
    const float* b_conv = (const float*)d_in[10];
    const float* W_ih   = (const float*)d_in[11];
    const float* W_hh   = (const float*)d_in[12];
    const float* b_ih   = (const float*)d_in[13];
    const float* b_hh   = (const float*)d_in[14];
    const float* W_ihl  = (const float*)d_in[15];
    const float* W_hhl  = (const float*)d_in[16];
    const float* b_ihl  = (const float*)d_in[17];
    const float* b_hhl  = (const float*)d_in[18];
    const float* W1     = (const float*)d_in[19];
    const float* b1     = (const float*)d_in[20];
    const float* W2     = (const float*)d_in[21];
    const float* b2     = (const float*)d_in[22];
    float* outp = (float*)d_out;

    char* ws = (char*)d_ws;
    size_t off = 0;
    auto alloc = [&](size_t bytes) -> char* {
        char* p = ws + off;
        off += (bytes + 255) & ~(size_t)255;
        return p;
    };
    u16*   h1     = (u16*)  alloc((size_t)NE * 128 * 2);
    u16*   Wt     = (u16*)  alloc((size_t)64 * WT_STRIDE * 2);
    u16*   outb   = (u16*)  alloc((size_t)NN * 64 * 2);
    float* h      = (float*)alloc((size_t)NN * 64 * 4);
    float* agg    = (float*)alloc((size_t)NN * 64 * 4);
    float* deg    = (float*)alloc(NN * 4);               // deg/gstart/gend contiguous
    int*   gstart = (int*)  alloc(NGR * 4);
    int*   gend   = (int*)  alloc(NGR * 4);
    float* hl     = (float*)alloc(NGR * 64 * 4);
    float* cl     = (float*)alloc(NGR * 64 * 4);
    float* qstar  = (float*)alloc(NGR * 128 * 4);
    float* WTih   = (float*)alloc(12288 * 4);
    float* WThh   = (float*)alloc(12288 * 4);
    float* WTihl  = (float*)alloc(32768 * 4);
    float* WThhl  = (float*)alloc(16384 * 4);
    float* WT1    = (float*)alloc(8192 * 4);
    if (off > ws_size) return;

    // one memset covers deg + gstart + gend (allocated contiguously)
    size_t zspan = (size_t)((char*)(gend + NGR) - (char*)deg);
    hipMemsetAsync(deg, 0, zspan, stream);

    k_pre<<<29870, 256, 0, stream>>>(x, ea, ei, batch, W0, b0, We1, be1, We2, be2,
                                     W_ih, W_hh, W_ihl, W_hhl, W1,
                                     h, outb, h1, Wt, deg, gstart, gend,
                                     WTih, WThh, WTihl, WThhl, WT1,
                                     agg, hl, cl, qstar);

    dim3 mgrid(313, 4, 1);
    for (int it = 0; it < 3; ++it) {
        k_msg<<<mgrid, 128, 0, stream>>>(outb, h1, Wt, ei, agg);
        k_gru<<<313, 256, 0, stream>>>(h, outb, agg, deg, b_conv,
                                       WTih, WThh, b_ih, b_hh);
    }
    for (int st = 0; st < 3; ++st) {
        k_lstm<<<32, 256, 0, stream>>>(hl, cl, qstar, WTihl, WThhl, b_ihl, b_hhl);
        k_pool<<<NGR, 256, 0, stream>>>(h, hl, gstart, gend, qstar);
    }
    k_readout<<<32, 256, 0, stream>>>(qstar, WT1, b1, W2, b2, outp);
}